// Round 15
// baseline (82.970 us; speedup 1.0000x reference)
//
#include <hip/hip_runtime.h>
#include <hip/hip_bf16.h>

#define IMG    512
#define KSZ    11
#define HALO   5
#define STRIP  64          // cols per block (4 waves x 16)
#define PANEL  16          // rows per H panel / V step
#define WPS    84          // per-wave ring pair-row stride in u32 (5*16 + 4 pad)
#define WRSZ   (24 * WPS)  // per-wave ring size in u32 (2016)

typedef short bf16x8 __attribute__((ext_vector_type(8)));
typedef float f32x4  __attribute__((ext_vector_type(4)));
union S8 { bf16x8 v; ushort u16[8]; uint u32[4]; };

__device__ __forceinline__ uint cvtpk(float lo, float hi) {
    uint r;
    asm("v_cvt_pk_bf16_f32 %0, %1, %2" : "=v"(r) : "v"(lo), "v"(hi));
    return r;
}
__device__ __forceinline__ float2 pk_mul(float2 a, float2 b) {
    float2 d;
    asm("v_pk_mul_f32 %0, %1, %2" : "=v"(d) : "v"(a), "v"(b));
    return d;
}
__device__ __forceinline__ ushort f2bf(float f) {   // prologue-only
    union { __hip_bfloat16 h; ushort u; } c;
    c.h = __float2bfloat16(f);
    return c.u;
}

// MFMA 16x16x32 bf16 layouts (validated end-to-end R12-R14):
//   A: row=lane&15, k=8*(lane>>4)+i   B: col=lane&15, k=8*(lane>>4)+i
//   D: col=lane&15, row=4*(lane>>4)+reg
// R15 DISCOVERY: ring writes (H) and reads (V) both touch only column
// wv*16+cj -> NO cross-wave data flow. Ring is now PER-WAVE and the two
// per-step __syncthreads are DELETED (same-wave LDS deps ordered by
// lgkmcnt). Pad stride WPS=84: H-write banks (8q+cj)%32 and V-read banks
// (16q+cj)%32 are both exactly 2-way (free, m136).
// H Toeplitz g[k-cj-3] (window -8); V g[k-cj-1]; ring row = abs+6 mod 48.

__global__ __launch_bounds__(256)
void dssim_mfma_kernel(const float* __restrict__ x,
                       const float* __restrict__ y,
                       const float* __restrict__ kern,
                       float* __restrict__ out)
{
    __shared__ float  sgf[16];
    __shared__ ushort gext[64];
    __shared__ uint   Wring[4 * WRSZ];   // 32256 B, per-wave partitioned
    __shared__ float  wsum[4];

    const int tid = threadIdx.x;
    const int l   = tid & 63;
    const int wv  = tid >> 6;
    const int q   = l >> 4;
    const int cj  = l & 15;
    const int wb  = wv * WRSZ;      // this wave's ring base (u32)

    if (tid < KSZ) {
        float s = 0.f;
        #pragma unroll
        for (int j = 0; j < KSZ; ++j) s += kern[tid * KSZ + j];
        sgf[tid] = s;   // k2d rows sum to g (sum(g)==1)
    }
    // each wave zeroes ITS OWN pad pair-rows 0..2 (ring rows 0..5)
    for (int i = l; i < 3 * WPS; i += 64) Wring[wb + i] = 0u;
    __syncthreads();               // publish sgf to wave 0's gext writers
    if (tid < 64) {
        const int d = tid - 18;    // slot 18+d holds g[d]
        gext[tid] = (d >= 0 && d < KSZ) ? f2bf(sgf[d]) : (ushort)0;
    }
    __syncthreads();               // publish gext to all waves (last barrier
                                   // before the epilogue reduction)

    // Toeplitz frags: H g[k-cj-3] -> slot 15+k-cj; V g[k-cj-1] -> 17+k-cj.
    S8 tgh, tgv;
    #pragma unroll
    for (int ii = 0; ii < 8; ++ii) {
        tgh.u16[ii] = gext[15 + q * 8 + ii - cj];
        tgv.u16[ii] = gext[17 + q * 8 + ii - cj];
    }

    const int plane  = blockIdx.z;
    const int half   = blockIdx.y;
    const int cstrip = blockIdx.x * STRIP;
    const int base   = plane * (IMG * IMG);

    const int  cb    = cstrip - 8 + 16 * wv + 8 * q;   // multiple of 8
    const bool colok = (cb >= 0) && (cb + 8 <= IMG);
    const float* xp  = x + base + cb;
    const float* yp  = y + base + cb;

    // Row-split: h=0 -> V(0..15) via t=0..16; h=1 primes t=15,16 then
    // V(16..31) via t=17..32.
    const int t0   = half ? 15 : 0;
    const int t1   = half ? 32 : 16;
    const int vmin = half ? 17 : 1;

    f32x4 xa, xb, ya, yb;
    auto load8 = [&](int t) {
        const int r = t * PANEL + cj;
        if (r < IMG && colok) {
            const float* px = xp + r * IMG;
            const float* py = yp + r * IMG;
            xa = *(const f32x4*)px;  xb = *(const f32x4*)(px + 4);
            ya = *(const f32x4*)py;  yb = *(const f32x4*)(py + 4);
        } else {
            const f32x4 zz = {0.f, 0.f, 0.f, 0.f};
            xa = zz; xb = zz; ya = zz; yb = zz;
        }
    };

    load8(t0);

    const f32x4 z0 = {0.f, 0.f, 0.f, 0.f};
    const float C1 = 1e-4f, C2 = 9e-4f;
    float local = 0.f;
    int hb = (8 * t0) % 24;

    for (int t = t0; t <= t1; ++t) {
        // ---- build 5 bf16 A-frags in registers ----
        float2 x01 = {xa[0], xa[1]}, x23 = {xa[2], xa[3]};
        float2 x45 = {xb[0], xb[1]}, x67 = {xb[2], xb[3]};
        float2 y01 = {ya[0], ya[1]}, y23 = {ya[2], ya[3]};
        float2 y45 = {yb[0], yb[1]}, y67 = {yb[2], yb[3]};
        S8 fx, fy, fxx, fyy, fxy;
        #pragma unroll
        for (int w = 0; w < 4; ++w) {
            const float2 xv = (w == 0) ? x01 : (w == 1) ? x23 : (w == 2) ? x45 : x67;
            const float2 yv = (w == 0) ? y01 : (w == 1) ? y23 : (w == 2) ? y45 : y67;
            const float2 xxv = pk_mul(xv, xv);
            const float2 yyv = pk_mul(yv, yv);
            const float2 xyv = pk_mul(xv, yv);
            fx .u32[w] = cvtpk(xv.x,  xv.y);
            fy .u32[w] = cvtpk(yv.x,  yv.y);
            fxx.u32[w] = cvtpk(xxv.x, xxv.y);
            fyy.u32[w] = cvtpk(yyv.x, yyv.y);
            fxy.u32[w] = cvtpk(xyv.x, xyv.y);
        }

        if (t < t1) load8(t + 1);   // HBM latency hides under MFMA + V below

        // ---- H(t): 5 MFMAs -> pair-packed per-wave ring writes ----
        {
            int p0 = hb + 2 * q + 3;  if (p0 >= 24) p0 -= 24;
            int p1 = p0 + 1;          if (p1 >= 24) p1 -= 24;
            const int rw0 = wb + p0 * WPS + cj;
            const int rw1 = wb + p1 * WPS + cj;
            f32x4 d;
            d = __builtin_amdgcn_mfma_f32_16x16x32_bf16(fx.v,  tgh.v, z0, 0, 0, 0);
            Wring[rw0 +  0] = cvtpk(d[0], d[1]);
            Wring[rw1 +  0] = cvtpk(d[2], d[3]);
            d = __builtin_amdgcn_mfma_f32_16x16x32_bf16(fy.v,  tgh.v, z0, 0, 0, 0);
            Wring[rw0 + 16] = cvtpk(d[0], d[1]);
            Wring[rw1 + 16] = cvtpk(d[2], d[3]);
            d = __builtin_amdgcn_mfma_f32_16x16x32_bf16(fxx.v, tgh.v, z0, 0, 0, 0);
            Wring[rw0 + 32] = cvtpk(d[0], d[1]);
            Wring[rw1 + 32] = cvtpk(d[2], d[3]);
            d = __builtin_amdgcn_mfma_f32_16x16x32_bf16(fyy.v, tgh.v, z0, 0, 0, 0);
            Wring[rw0 + 48] = cvtpk(d[0], d[1]);
            Wring[rw1 + 48] = cvtpk(d[2], d[3]);
            d = __builtin_amdgcn_mfma_f32_16x16x32_bf16(fxy.v, tgh.v, z0, 0, 0, 0);
            Wring[rw0 + 64] = cvtpk(d[0], d[1]);
            Wring[rw1 + 64] = cvtpk(d[2], d[3]);
        }

        // ---- V(t-1) + SSIM (no barrier: same-wave lgkmcnt orders LDS) ----
        if (t >= vmin) {
            const int vb = (hb >= 8) ? hb - 8 : hb + 16;   // (8(t-1)) mod 24
            int vr[4];
            #pragma unroll
            for (int ii = 0; ii < 4; ++ii) {
                int pp = vb + 4 * q + ii;  if (pp >= 24) pp -= 24;
                vr[ii] = wb + pp * WPS + cj;
            }
            f32x4 vf[5];
            #pragma unroll
            for (int f = 0; f < 5; ++f) {
                S8 b;
                #pragma unroll
                for (int ii = 0; ii < 4; ++ii) b.u32[ii] = Wring[vr[ii] + f * 16];
                vf[f] = __builtin_amdgcn_mfma_f32_16x16x32_bf16(tgv.v, b.v, z0, 0, 0, 0);
            }
            #pragma unroll
            for (int r = 0; r < 4; ++r) {
                const float mx  = vf[0][r], my  = vf[1][r];
                const float exx = vf[2][r], eyy = vf[3][r], exy = vf[4][r];
                const float sxv = fmaf(-mx, mx, exx);
                const float syv = fmaf(-my, my, eyy);
                const float sxy = fmaf(-mx, my, exy);
                const float num = fmaf(2.f, mx * my, C1) * fmaf(2.f, sxy, C2);
                const float den = fmaf(mx, mx, fmaf(my, my, C1)) * (sxv + syv + C2);
                const float ssim = __fdividef(num, den + 1e-8f);
                local += (1.f - ssim) * 0.5f;
            }
        }

        hb += 8;  if (hb >= 24) hb -= 24;
    }

    // ---- block reduction, one atomic per block ----
    #pragma unroll
    for (int o = 32; o > 0; o >>= 1) local += __shfl_down(local, o, 64);
    if (l == 0) wsum[wv] = local;
    __syncthreads();
    if (tid == 0) {
        const float s = wsum[0] + wsum[1] + wsum[2] + wsum[3];
        atomicAdd(out, s * (1.f / 25165824.f));   // / (32*3*512*512)
    }
}

extern "C" void kernel_launch(void* const* d_in, const int* in_sizes, int n_in,
                              void* d_out, int out_size, void* d_ws, size_t ws_size,
                              hipStream_t stream)
{
    const float* x    = (const float*)d_in[0];
    const float* y    = (const float*)d_in[1];
    const float* kern = (const float*)d_in[2];
    float* out = (float*)d_out;

    hipMemsetAsync(out, 0, sizeof(float), stream);

    dim3 grid(IMG / STRIP, 2, 32 * 3);   // 8 strips x 2 halves x 96 planes
    dssim_mfma_kernel<<<grid, 256, 0, stream>>>(x, y, kern, out);
}

// Round 16
// 76.238 us; speedup vs baseline: 1.0883x; 1.0883x over previous
//
#include <hip/hip_runtime.h>
#include <hip/hip_bf16.h>

#define IMG    512
#define KSZ    11
#define HALO   5
#define STRIP  64          // cols per block (4 waves x 16)
#define PANEL  16          // rows per H panel / V step
#define WPS    84          // per-wave ring pair-row stride in u32 (5*16 + 4 pad)
#define NPAIR  32          // ring pair-rows (64 rows) -> &31 indexing
#define WRSZ   (NPAIR * WPS)

typedef short bf16x8 __attribute__((ext_vector_type(8)));
typedef float f32x4  __attribute__((ext_vector_type(4)));
union S8 { bf16x8 v; ushort u16[8]; uint u32[4]; };

__device__ __forceinline__ uint cvtpk(float lo, float hi) {
    uint r;
    asm("v_cvt_pk_bf16_f32 %0, %1, %2" : "=v"(r) : "v"(lo), "v"(hi));
    return r;
}
__device__ __forceinline__ float2 pk_mul(float2 a, float2 b) {
    float2 d;
    asm("v_pk_mul_f32 %0, %1, %2" : "=v"(d) : "v"(a), "v"(b));
    return d;
}
__device__ __forceinline__ ushort f2bf(float f) {   // prologue-only
    union { __hip_bfloat16 h; ushort u; } c;
    c.h = __float2bfloat16(f);
    return c.u;
}

// MFMA 16x16x32 bf16 layouts (validated end-to-end R12-R15):
//   A: row=lane&15, k=8*(lane>>4)+i   B: col=lane&15, k=8*(lane>>4)+i
//   D: col=lane&15, row=4*(lane>>4)+reg
// R16: V runs at LAG 2 (V(t-2) at iter t) so V's ds_reads never chase
// same-iter H ds_writes (the R15 serial chain). Needs 64-row ring:
// live span = V-read [16t-38,16t-7] U H-write [16t+6,16t+21] in ring rows
// = 60 rows <= 64. Pair-rows mod 32 (&31). V(s) pair base vb=(8s)&31 =
// hb^16 at s=t-2. Per-wave ring, no main-loop barriers (R15).
// H Toeplitz g[k-cj-3] (window -8); V g[k-cj-1]; ring row = abs+6 mod 64.
// Loads double-buffered (2-deep): load8(t+2) issued at iter t.

__global__ __launch_bounds__(256)
void dssim_mfma_kernel(const float* __restrict__ x,
                       const float* __restrict__ y,
                       const float* __restrict__ kern,
                       float* __restrict__ out)
{
    __shared__ float  sgf[16];
    __shared__ ushort gext[64];
    __shared__ uint   Wring[4 * WRSZ];   // 43008 B, per-wave partitioned
    __shared__ float  wsum[4];

    const int tid = threadIdx.x;
    const int l   = tid & 63;
    const int wv  = tid >> 6;
    const int q   = l >> 4;
    const int cj  = l & 15;
    const int wb  = wv * WRSZ;

    if (tid < KSZ) {
        float s = 0.f;
        #pragma unroll
        for (int j = 0; j < KSZ; ++j) s += kern[tid * KSZ + j];
        sgf[tid] = s;   // k2d rows sum to g (sum(g)==1)
    }
    // zero pad pair-rows 0..2 (ring rows 0..5 = abs -6..-1) of OWN ring
    for (int i = l; i < 3 * WPS; i += 64) Wring[wb + i] = 0u;
    __syncthreads();
    if (tid < 64) {
        const int d = tid - 18;    // slot 18+d holds g[d]
        gext[tid] = (d >= 0 && d < KSZ) ? f2bf(sgf[d]) : (ushort)0;
    }
    __syncthreads();               // last barrier before epilogue

    // Toeplitz frags: H g[k-cj-3] -> slot 15+k-cj; V g[k-cj-1] -> 17+k-cj.
    S8 tgh, tgv;
    #pragma unroll
    for (int ii = 0; ii < 8; ++ii) {
        tgh.u16[ii] = gext[15 + q * 8 + ii - cj];
        tgv.u16[ii] = gext[17 + q * 8 + ii - cj];
    }

    const int plane  = blockIdx.z;
    const int half   = blockIdx.y;
    const int cstrip = blockIdx.x * STRIP;
    const int base   = plane * (IMG * IMG);

    const int  cb    = cstrip - 8 + 16 * wv + 8 * q;   // multiple of 8
    const bool colok = (cb >= 0) && (cb + 8 <= IMG);
    const float* xp  = x + base + cb;
    const float* yp  = y + base + cb;

    // half 0: iters t=0..17,  H for t<=16, V(s=t-2) for t>=2  (s=0..15)
    // half 1: iters t=15..33, H for t<=32, V(s=t-2) for t>=18 (s=16..31)
    const int t0   = half ? 15 : 0;
    const int t1   = half ? 33 : 17;
    const int hmax = half ? 32 : 16;
    const int vmin = half ? 18 : 2;

    const f32x4 z0 = {0.f, 0.f, 0.f, 0.f};
    const float C1 = 1e-4f, C2 = 9e-4f;
    float local = 0.f;
    int hb = (8 * t0) & 31;

    // double-buffered load registers (2-deep pipeline)
    f32x4 xa0, xb0, ya0, yb0, xa1, xb1, ya1, yb1;

    auto load8 = [&](int t, f32x4& xa, f32x4& xb, f32x4& ya, f32x4& yb) {
        const int r = t * PANEL + cj;
        if (r < IMG && colok) {
            const float* px = xp + r * IMG;
            const float* py = yp + r * IMG;
            xa = *(const f32x4*)px;  xb = *(const f32x4*)(px + 4);
            ya = *(const f32x4*)py;  yb = *(const f32x4*)(py + 4);
        } else {
            xa = z0; xb = z0; ya = z0; yb = z0;
        }
    };

    auto step = [&](int t, f32x4& xa, f32x4& xb, f32x4& ya, f32x4& yb) {
        // ---- V(t-2) + SSIM first: ring data is >=1 iter old, no wait ----
        if (t >= vmin) {
            const int vb = hb ^ 16;            // (8(t-2)) & 31
            int vr[4];
            #pragma unroll
            for (int ii = 0; ii < 4; ++ii)
                vr[ii] = wb + ((vb + 4 * q + ii) & 31) * WPS + cj;
            f32x4 vf[5];
            #pragma unroll
            for (int f = 0; f < 5; ++f) {
                S8 b;
                #pragma unroll
                for (int ii = 0; ii < 4; ++ii) b.u32[ii] = Wring[vr[ii] + f * 16];
                vf[f] = __builtin_amdgcn_mfma_f32_16x16x32_bf16(tgv.v, b.v, z0, 0, 0, 0);
            }
            #pragma unroll
            for (int r = 0; r < 4; ++r) {
                const float mx  = vf[0][r], my  = vf[1][r];
                const float exx = vf[2][r], eyy = vf[3][r], exy = vf[4][r];
                const float sxv = fmaf(-mx, mx, exx);
                const float syv = fmaf(-my, my, eyy);
                const float sxy = fmaf(-mx, my, exy);
                const float num = fmaf(2.f, mx * my, C1) * fmaf(2.f, sxy, C2);
                const float den = fmaf(mx, mx, fmaf(my, my, C1)) * (sxv + syv + C2);
                const float ssim = __fdividef(num, den + 1e-8f);
                local += (1.f - ssim) * 0.5f;
            }
        }

        if (t <= hmax) {
            // ---- build 5 bf16 A-frags (vmcnt: loads issued 2 iters ago) ----
            float2 x01 = {xa[0], xa[1]}, x23 = {xa[2], xa[3]};
            float2 x45 = {xb[0], xb[1]}, x67 = {xb[2], xb[3]};
            float2 y01 = {ya[0], ya[1]}, y23 = {ya[2], ya[3]};
            float2 y45 = {yb[0], yb[1]}, y67 = {yb[2], yb[3]};
            S8 fx, fy, fxx, fyy, fxy;
            #pragma unroll
            for (int w = 0; w < 4; ++w) {
                const float2 xv = (w == 0) ? x01 : (w == 1) ? x23 : (w == 2) ? x45 : x67;
                const float2 yv = (w == 0) ? y01 : (w == 1) ? y23 : (w == 2) ? y45 : y67;
                const float2 xxv = pk_mul(xv, xv);
                const float2 yyv = pk_mul(yv, yv);
                const float2 xyv = pk_mul(xv, yv);
                fx .u32[w] = cvtpk(xv.x,  xv.y);
                fy .u32[w] = cvtpk(yv.x,  yv.y);
                fxx.u32[w] = cvtpk(xxv.x, xxv.y);
                fyy.u32[w] = cvtpk(yyv.x, yyv.y);
                fxy.u32[w] = cvtpk(xyv.x, xyv.y);
            }

            // ---- refill this buffer for t+2 (regs just freed) ----
            if (t + 2 <= hmax) load8(t + 2, xa, xb, ya, yb);

            // ---- H(t): 5 MFMAs -> ring (consumed at iter t+1/t+2) ----
            const int p0  = (hb + 2 * q + 3) & 31;
            const int p1  = (p0 + 1) & 31;
            const int rw0 = wb + p0 * WPS + cj;
            const int rw1 = wb + p1 * WPS + cj;
            f32x4 d;
            d = __builtin_amdgcn_mfma_f32_16x16x32_bf16(fx.v,  tgh.v, z0, 0, 0, 0);
            Wring[rw0 +  0] = cvtpk(d[0], d[1]);
            Wring[rw1 +  0] = cvtpk(d[2], d[3]);
            d = __builtin_amdgcn_mfma_f32_16x16x32_bf16(fy.v,  tgh.v, z0, 0, 0, 0);
            Wring[rw0 + 16] = cvtpk(d[0], d[1]);
            Wring[rw1 + 16] = cvtpk(d[2], d[3]);
            d = __builtin_amdgcn_mfma_f32_16x16x32_bf16(fxx.v, tgh.v, z0, 0, 0, 0);
            Wring[rw0 + 32] = cvtpk(d[0], d[1]);
            Wring[rw1 + 32] = cvtpk(d[2], d[3]);
            d = __builtin_amdgcn_mfma_f32_16x16x32_bf16(fyy.v, tgh.v, z0, 0, 0, 0);
            Wring[rw0 + 48] = cvtpk(d[0], d[1]);
            Wring[rw1 + 48] = cvtpk(d[2], d[3]);
            d = __builtin_amdgcn_mfma_f32_16x16x32_bf16(fxy.v, tgh.v, z0, 0, 0, 0);
            Wring[rw0 + 64] = cvtpk(d[0], d[1]);
            Wring[rw1 + 64] = cvtpk(d[2], d[3]);
        }

        hb = (hb + 8) & 31;
    };

    load8(t0,     xa0, xb0, ya0, yb0);
    load8(t0 + 1, xa1, xb1, ya1, yb1);

    for (int tt = t0; tt <= t1; tt += 2) {
        step(tt, xa0, xb0, ya0, yb0);
        if (tt + 1 <= t1) step(tt + 1, xa1, xb1, ya1, yb1);
    }

    // ---- block reduction, one atomic per block ----
    #pragma unroll
    for (int o = 32; o > 0; o >>= 1) local += __shfl_down(local, o, 64);
    if (l == 0) wsum[wv] = local;
    __syncthreads();
    if (tid == 0) {
        const float s = wsum[0] + wsum[1] + wsum[2] + wsum[3];
        atomicAdd(out, s * (1.f / 25165824.f));   // / (32*3*512*512)
    }
}

extern "C" void kernel_launch(void* const* d_in, const int* in_sizes, int n_in,
                              void* d_out, int out_size, void* d_ws, size_t ws_size,
                              hipStream_t stream)
{
    const float* x    = (const float*)d_in[0];
    const float* y    = (const float*)d_in[1];
    const float* kern = (const float*)d_in[2];
    float* out = (float*)d_out;

    hipMemsetAsync(out, 0, sizeof(float), stream);

    dim3 grid(IMG / STRIP, 2, 32 * 3);   // 8 strips x 2 halves x 96 planes
    dssim_mfma_kernel<<<grid, 256, 0, stream>>>(x, y, kern, out);
}